// Round 12
// baseline (312.173 us; speedup 1.0000x reference)
//
#include <hip/hip_runtime.h>
#include <hip/hip_bf16.h>

// 2-layer LSTM (H=32, T=512, I=1) + FC(1) + ReLU, fused, 4-wave unit-split,
// DUAL-STREAM. Block = 256 threads = 4 waves: w0/w1 = layer-0 units
// 0-15/16-31, w2/w3 = layer-1 units 0-15/16-31 (one step behind). Each wave
// processes TWO independent batch-groups (streams) sharing the same weight
// registers: stream A = batches blk*8+{0..3}, stream B = blk*8+{4..7}.
// The two CELL chains interleave at compile time, packing the quarter-rate
// trans pipe (the measured limiter: ~28 cyc effective per trans op from
// serial chains). 8 batches/block, 512 blocks -> 2 waves/SIMD x 2 streams.
// Gate (tau, unit 16U+4m+q) at D slot (tau,q) -> cndmask select; cell
// update lane-local; h exchanged as packed bf16 pairs via LDS (double-
// buffered by parity, ONE __syncthreads per step guarding both streams).
// Bias in MFMA C-in; merged-rcp CELL (7 trans); pre-zeroed LDS.

typedef __attribute__((ext_vector_type(8))) short bf16x8;
typedef __attribute__((ext_vector_type(4))) float f32x4;
typedef __attribute__((ext_vector_type(4))) int   i32x4;

#define HID 32
#define SEQ 512
#define L2E 1.4426950408889634f

static __device__ __forceinline__ float fexp2(float x){ return __builtin_amdgcn_exp2f(x); }
static __device__ __forceinline__ float frcp (float x){ return __builtin_amdgcn_rcpf(x); }
static __device__ __forceinline__ short f2bf(float f){
  unsigned u = __builtin_bit_cast(unsigned, f);
  u = (u + 0x7fffu + ((u >> 16) & 1u)) >> 16;
  return (short)u;
}

// fused LSTM cell, merged-rcp form. Gates pre-scaled (i,f,o by -log2e;
// g by +2log2e):  I=e^-i, F=e^-f, O=e^-o, G=e^{2g}.
#define CELL(gi, gf, gg, go, cvr, hout) do {                         \
  const float I_ = fexp2(gi), G_ = fexp2(gg);                        \
  const float F_ = fexp2(gf), O_ = fexp2(go);                        \
  const float a_ = 1.f + I_, b_ = 1.f + G_, c_ = 1.f + F_;           \
  const float P1_ = a_ * b_;                                         \
  const float R_  = frcp(c_ * P1_);                                  \
  const float fv_ = P1_ * R_;                                        \
  const float ig_ = (G_ - 1.f) * (c_ * R_);                          \
  (cvr) = fmaf(fv_, (cvr), ig_);                                     \
  const float C2_ = fexp2((cvr) * (2.f * L2E));                      \
  (hout) = (C2_ - 1.f) * frcp((1.f + O_) * (1.f + C2_));             \
} while (0)

// select gate (tau, unit 16U+4m+q) from D slot (tau, q) of accumulator tab
#define GSEL(Atab, t) ({                                  \
  const float e_ = (q & 1) ? Atab[t][1] : Atab[t][0];     \
  const float o_ = (q & 1) ? Atab[t][3] : Atab[t][2];     \
  (q & 2) ? o_ : e_; })

// pack own h with neighbor (lane col+4) via DPP row_ror:12 -> bf16 pair
#define HPACK(hn, pk) do {                                                    \
  const float hp_ = __builtin_bit_cast(float,                                 \
      __builtin_amdgcn_mov_dpp(__builtin_bit_cast(int, (hn)), 0x12C, 0xF, 0xF, false)); \
  asm("v_cvt_pk_bf16_f32 %0, %1, %2" : "=v"(pk) : "v"(hn), "v"(hp_));         \
} while (0)

__global__ __launch_bounds__(256, 4) void lstm2_ds2_kernel(
    const float* __restrict__ x,
    const float* __restrict__ Wih0, const float* __restrict__ Whh0,
    const float* __restrict__ bih0, const float* __restrict__ bhh0,
    const float* __restrict__ Wih1, const float* __restrict__ Whh1,
    const float* __restrict__ bih1, const float* __restrict__ bhh1,
    const float* __restrict__ Wfc, const float* __restrict__ bfc,
    float* __restrict__ out)
{
  const int tid = threadIdx.x;
  const int w   = tid >> 6;          // 0,1: L0 halves; 2,3: L1 halves
  const int l   = tid & 63;
  const int m   = l >> 4;            // A/B fragment k-group (units 8m..8m+7)
  const int col = l & 15;            // MFMA N col
  const int q   = col >> 2;          // D row-subselect -> owned unit
  const int s   = col & 3;           // batch slot within stream
  const int U   = w & 1;             // unit half
  const int unit  = 16 * U + 4 * m + q;   // owned unit within layer

  __shared__ int   bufH0[2][128];    // [parity][stream*64 + s*16 + pair]
  __shared__ int   bufH1[2][128];
  __shared__ float bufFC[2][2][4];   // [stream][half][batch]

  // zero-init exchange buffers (kills all t=0 special cases)
  ((int*)bufH0)[tid] = 0;
  ((int*)bufH1)[tid] = 0;
  __syncthreads();

  // ---- weights (shared by both streams): tile tau row rho = gate
  //      (tau, unit 16U+rho). Rows pre-scaled: i,f,o -> -log2e; g -> +2log2e.
  bf16x8 wfR[4], wfI[4];   // recurrent (Whh) / L1-input (Wih1) fragments
  f32x4  cb[4];            // MFMA C-in: per-slot gate bias (pre-scaled)
  float  w0x[4];           // L0: sc * Wih0 for owned unit
  const float* Wrec = (w < 2) ? Whh0 : Whh1;
  const float* Bi   = (w < 2) ? bih0 : bih1;
  const float* Bh   = (w < 2) ? bhh0 : bhh1;
  #pragma unroll
  for (int t = 0; t < 4; ++t) {
    const float sc = (t == 2) ? (2.0f * L2E) : (-L2E);
    const int ga = t * 32 + 16 * U + col;
    #pragma unroll
    for (int j = 0; j < 8; ++j) {
      wfR[t][j] = f2bf(sc * Wrec[ga * HID + (8 * m + j)]);
      wfI[t][j] = (w >= 2) ? f2bf(sc * Wih1[ga * HID + (8 * m + j)]) : (short)0;
    }
    #pragma unroll
    for (int r = 0; r < 4; ++r) {
      const int g = t * 32 + 16 * U + 4 * m + r;
      cb[t][r] = sc * (Bi[g] + Bh[g]);
    }
    w0x[t] = (w < 2) ? sc * Wih0[t * 32 + unit] : 0.f;
  }
  const float wfc = (w >= 2) ? Wfc[unit] : 0.f;

  float cvA = 0.f, hnA = 0.f, cvB = 0.f, hnB = 0.f;
  const float* xbA = x + (size_t)(blockIdx.x * 8 + s) * SEQ;       // stream A
  const float* xbB = x + (size_t)(blockIdx.x * 8 + 4 + s) * SEQ;   // stream B
  const int  rdA = s * 16 + 4 * m;                      // b128 read base
  const int  wrP = s * 16 + 8 * U + 2 * m + (q >> 1);   // b32 write slot
  const bool wr  = ((q & 1) == 0);                      // even-q lanes write

  for (int k = 0; k < SEQ / 4; ++k) {
    float4 xvA = {0.f,0.f,0.f,0.f}, xvB = {0.f,0.f,0.f,0.f};
    if (w < 2) {
      xvA = *reinterpret_cast<const float4*>(xbA + k * 4);
      xvB = *reinterpret_cast<const float4*>(xbB + k * 4);
    }
    #pragma unroll
    for (int uu = 0; uu < 4; ++uu) {
      const int par = uu & 1;
      if (w < 2) {
        // ---- L0 both streams: h0(i) from h0(i-1) at parity (i+1)&1 ----
        const i32x4 hvA = *(const i32x4*)&bufH0[par ^ 1][rdA];
        const i32x4 hvB = *(const i32x4*)&bufH0[par ^ 1][64 + rdA];
        const bf16x8 hfA = __builtin_bit_cast(bf16x8, hvA);
        const bf16x8 hfB = __builtin_bit_cast(bf16x8, hvB);
        f32x4 AA[4], AB[4];
        #pragma unroll
        for (int t = 0; t < 4; ++t) {
          AA[t] = __builtin_amdgcn_mfma_f32_16x16x32_bf16(wfR[t], hfA, cb[t], 0, 0, 0);
          AB[t] = __builtin_amdgcn_mfma_f32_16x16x32_bf16(wfR[t], hfB, cb[t], 0, 0, 0);
        }
        const float xtA = (uu == 0) ? xvA.x : (uu == 1) ? xvA.y : (uu == 2) ? xvA.z : xvA.w;
        const float xtB = (uu == 0) ? xvB.x : (uu == 1) ? xvB.y : (uu == 2) ? xvB.z : xvB.w;
        float gA[4], gB[4];
        #pragma unroll
        for (int t = 0; t < 4; ++t) {
          gA[t] = fmaf(w0x[t], xtA, GSEL(AA, t));
          gB[t] = fmaf(w0x[t], xtB, GSEL(AB, t));
        }
        CELL(gA[0], gA[1], gA[2], gA[3], cvA, hnA);   // two independent
        CELL(gB[0], gB[1], gB[2], gB[3], cvB, hnB);   // chains interleave
        int pkA, pkB;
        HPACK(hnA, pkA);
        HPACK(hnB, pkB);
        if (wr) { bufH0[par][wrP] = pkA; bufH0[par][64 + wrP] = pkB; }
      } else if (uu > 0 || k > 0) {
        // ---- L1 both streams: h1(i-1); reads h0(i-1) par^1, h1(i-2) par ----
        const i32x4 h0vA = *(const i32x4*)&bufH0[par ^ 1][rdA];
        const i32x4 h1vA = *(const i32x4*)&bufH1[par][rdA];
        const i32x4 h0vB = *(const i32x4*)&bufH0[par ^ 1][64 + rdA];
        const i32x4 h1vB = *(const i32x4*)&bufH1[par][64 + rdA];
        f32x4 AA[4], AB[4];
        __builtin_amdgcn_s_setprio(1);
        #pragma unroll
        for (int t = 0; t < 4; ++t) {
          AA[t] = __builtin_amdgcn_mfma_f32_16x16x32_bf16(
                    wfI[t], __builtin_bit_cast(bf16x8, h0vA), cb[t], 0, 0, 0);
          AB[t] = __builtin_amdgcn_mfma_f32_16x16x32_bf16(
                    wfI[t], __builtin_bit_cast(bf16x8, h0vB), cb[t], 0, 0, 0);
        }
        #pragma unroll
        for (int t = 0; t < 4; ++t) {
          AA[t] = __builtin_amdgcn_mfma_f32_16x16x32_bf16(
                    wfR[t], __builtin_bit_cast(bf16x8, h1vA), AA[t], 0, 0, 0);
          AB[t] = __builtin_amdgcn_mfma_f32_16x16x32_bf16(
                    wfR[t], __builtin_bit_cast(bf16x8, h1vB), AB[t], 0, 0, 0);
        }
        __builtin_amdgcn_s_setprio(0);
        float gA[4], gB[4];
        #pragma unroll
        for (int t = 0; t < 4; ++t) { gA[t] = GSEL(AA, t); gB[t] = GSEL(AB, t); }
        CELL(gA[0], gA[1], gA[2], gA[3], cvA, hnA);
        CELL(gB[0], gB[1], gB[2], gB[3], cvB, hnB);
        int pkA, pkB;
        HPACK(hnA, pkA);
        HPACK(hnB, pkB);
        if (wr) { bufH1[par ^ 1][wrP] = pkA; bufH1[par ^ 1][64 + wrP] = pkB; }
      }
      __syncthreads();
    }
  }

  // ---- epilogue: i = 512 for L1 -> h1(511); then FC + ReLU ----
  if (w >= 2) {
    const i32x4 h0vA = *(const i32x4*)&bufH0[1][rdA];        // h0(511)
    const i32x4 h1vA = *(const i32x4*)&bufH1[0][rdA];        // h1(510)
    const i32x4 h0vB = *(const i32x4*)&bufH0[1][64 + rdA];
    const i32x4 h1vB = *(const i32x4*)&bufH1[0][64 + rdA];
    f32x4 AA[4], AB[4];
    #pragma unroll
    for (int t = 0; t < 4; ++t) {
      AA[t] = __builtin_amdgcn_mfma_f32_16x16x32_bf16(
                wfI[t], __builtin_bit_cast(bf16x8, h0vA), cb[t], 0, 0, 0);
      AB[t] = __builtin_amdgcn_mfma_f32_16x16x32_bf16(
                wfI[t], __builtin_bit_cast(bf16x8, h0vB), cb[t], 0, 0, 0);
    }
    #pragma unroll
    for (int t = 0; t < 4; ++t) {
      AA[t] = __builtin_amdgcn_mfma_f32_16x16x32_bf16(
                wfR[t], __builtin_bit_cast(bf16x8, h1vA), AA[t], 0, 0, 0);
      AB[t] = __builtin_amdgcn_mfma_f32_16x16x32_bf16(
                wfR[t], __builtin_bit_cast(bf16x8, h1vB), AB[t], 0, 0, 0);
    }
    float gA[4], gB[4];
    #pragma unroll
    for (int t = 0; t < 4; ++t) { gA[t] = GSEL(AA, t); gB[t] = GSEL(AB, t); }
    CELL(gA[0], gA[1], gA[2], gA[3], cvA, hnA);
    CELL(gB[0], gB[1], gB[2], gB[3], cvB, hnB);
    float pA = hnA * wfc, pB = hnB * wfc;
    pA += __shfl_xor(pA, 4);  pB += __shfl_xor(pB, 4);
    pA += __shfl_xor(pA, 8);  pB += __shfl_xor(pB, 8);
    pA += __shfl_xor(pA, 16); pB += __shfl_xor(pB, 16);
    pA += __shfl_xor(pA, 32); pB += __shfl_xor(pB, 32);
    if (l < 4) { bufFC[0][U][l] = pA; bufFC[1][U][l] = pB; }
  }
  __syncthreads();
  if (w == 2 && l < 8) {
    const int st = l >> 2, b = l & 3;
    const float o = bufFC[st][0][b] + bufFC[st][1][b] + bfc[0];
    out[blockIdx.x * 8 + st * 4 + b] = o > 0.f ? o : 0.f;
  }
}

extern "C" void kernel_launch(void* const* d_in, const int* in_sizes, int n_in,
                              void* d_out, int out_size, void* d_ws, size_t ws_size,
                              hipStream_t stream) {
  const float* x    = (const float*)d_in[0];
  const float* Wih0 = (const float*)d_in[1];
  const float* Whh0 = (const float*)d_in[2];
  const float* bih0 = (const float*)d_in[3];
  const float* bhh0 = (const float*)d_in[4];
  const float* Wih1 = (const float*)d_in[5];
  const float* Whh1 = (const float*)d_in[6];
  const float* bih1 = (const float*)d_in[7];
  const float* bhh1 = (const float*)d_in[8];
  const float* Wfc  = (const float*)d_in[9];
  const float* bfc  = (const float*)d_in[10];

  const int B = 4096;
  const int grid = B / 8;   // 512 blocks x 4 waves = 2048 waves -> 2/SIMD x 2 streams
  lstm2_ds2_kernel<<<grid, 256, 0, stream>>>(
      x, Wih0, Whh0, bih0, bhh0, Wih1, Whh1, bih1, bhh1, Wfc, bfc,
      (float*)d_out);
}

// Round 13
// 197.692 us; speedup vs baseline: 1.5791x; 1.5791x over previous
//
#include <hip/hip_runtime.h>
#include <hip/hip_bf16.h>

// 2-layer LSTM (H=32, T=512, I=1) + FC(1) + ReLU, fused, ZERO-SELECT
// 8-wave unit-split, 16 batches/block. Block = 512 threads = 8 waves:
// w0-3 = layer-0 unit-groups 8V..8V+7, w4-7 = layer-1 unit-groups (one step
// behind). Weight rows permuted so tile t row rho = gate(rho&3) of unit
// (8V+4t+(rho>>2)): lane m's 4 D-regs of tile t = (i,f,g,o) of unit 8V+4t+m
// -> NO gate select at all. col = batch (16 distinct, no replication) ->
// chip MFMA count /4 vs R9. 2 cells/lane (ILP-2 trans chains). h exchanged
// as packed bf16 pairs via LDS (stride-20 rows, <=2-way conflicts; swizzle
// xor16 pairs m<->m^1, even-m lanes write). Double-buffered by parity, one
// __syncthreads per step. Bias in MFMA C-in; merged-rcp CELL (7 trans).
// 256 blocks x 8 waves = 2048 waves = 2/SIMD.

typedef __attribute__((ext_vector_type(8))) short bf16x8;
typedef __attribute__((ext_vector_type(4))) float f32x4;
typedef __attribute__((ext_vector_type(4))) int   i32x4;

#define HID 32
#define SEQ 512
#define L2E 1.4426950408889634f
#define LSTR 20   // LDS h-row stride in dwords (16 used + 4 pad, 16B-aligned)

static __device__ __forceinline__ float fexp2(float x){ return __builtin_amdgcn_exp2f(x); }
static __device__ __forceinline__ float frcp (float x){ return __builtin_amdgcn_rcpf(x); }
static __device__ __forceinline__ short f2bf(float f){
  unsigned u = __builtin_bit_cast(unsigned, f);
  u = (u + 0x7fffu + ((u >> 16) & 1u)) >> 16;
  return (short)u;
}

// fused LSTM cell, merged-rcp form. Gates pre-scaled (i,f,o by -log2e;
// g by +2log2e):  I=e^-i, F=e^-f, O=e^-o, G=e^{2g}.
#define CELL(gi, gf, gg, go, cvr, hout) do {                         \
  const float I_ = fexp2(gi), G_ = fexp2(gg);                        \
  const float F_ = fexp2(gf), O_ = fexp2(go);                        \
  const float a_ = 1.f + I_, b_ = 1.f + G_, c_ = 1.f + F_;           \
  const float P1_ = a_ * b_;                                         \
  const float R_  = frcp(c_ * P1_);                                  \
  const float fv_ = P1_ * R_;                                        \
  const float ig_ = (G_ - 1.f) * (c_ * R_);                          \
  (cvr) = fmaf(fv_, (cvr), ig_);                                     \
  const float C2_ = fexp2((cvr) * (2.f * L2E));                      \
  (hout) = (C2_ - 1.f) * frcp((1.f + O_) * (1.f + C2_));             \
} while (0)

// pack own h with partner lane (l^16 = m^1, same col) -> bf16 pair dword
#define HPACK(hv, pk) do {                                                    \
  const int pa_ = __builtin_amdgcn_ds_swizzle(__builtin_bit_cast(int, (hv)), 0x401F); \
  asm("v_cvt_pk_bf16_f32 %0, %1, %2" : "=v"(pk)                               \
      : "v"(hv), "v"(__builtin_bit_cast(float, pa_)));                        \
} while (0)

__global__ __launch_bounds__(512, 2) void lstm2_zs_kernel(
    const float* __restrict__ x,
    const float* __restrict__ Wih0, const float* __restrict__ Whh0,
    const float* __restrict__ bih0, const float* __restrict__ bhh0,
    const float* __restrict__ Wih1, const float* __restrict__ Whh1,
    const float* __restrict__ bih1, const float* __restrict__ bhh1,
    const float* __restrict__ Wfc, const float* __restrict__ bfc,
    float* __restrict__ out)
{
  const int tid = threadIdx.x;
  const int w   = tid >> 6;          // 0-3: L0 groups; 4-7: L1 groups
  const int l   = tid & 63;
  const int m   = l >> 4;            // k-group; D rows 4m..4m+3
  const int col = l & 15;            // batch slot (16 batches/block)
  const int V   = w & 3;             // unit group: units 8V..8V+7
  const bool isL1 = (w >= 4);

  __shared__ int   bufH0[2][16 * LSTR];   // [parity][batch*LSTR + unitpair]
  __shared__ int   bufH1[2][16 * LSTR];
  __shared__ float bufFC[4][16];

  // zero-init exchange buffers (kills all t=0 special cases)
  for (int i = tid; i < 2 * 16 * LSTR; i += 512) {
    ((int*)bufH0)[i] = 0;
    ((int*)bufH1)[i] = 0;
  }
  __syncthreads();

  // ---- weights: tile t row rho = gate(rho&3) of unit 8V+4t+(rho>>2).
  //      Lane supplies A row = col. Pre-scaled: i,f,o -> -log2e; g -> +2log2e.
  const float* Wrec = isL1 ? Whh1 : Whh0;
  const float* Bi   = isL1 ? bih1 : bih0;
  const float* Bh   = isL1 ? bhh1 : bhh0;
  const int   gcol  = col & 3;             // gate type this lane's A-row feeds
  const float scA   = (gcol == 2) ? (2.0f * L2E) : (-L2E);
  bf16x8 wfR[2], wfI[2];
  f32x4  cb[2];
  float  w0x[2][4];
  #pragma unroll
  for (int t = 0; t < 2; ++t) {
    const int ur = 8 * V + 4 * t + (col >> 2);   // A-row unit
    const int ga = gcol * 32 + ur;               // gate row in weight matrix
    #pragma unroll
    for (int j = 0; j < 8; ++j) {
      wfR[t][j] = f2bf(scA * Wrec[ga * HID + (8 * m + j)]);
      wfI[t][j] = isL1 ? f2bf(scA * Wih1[ga * HID + (8 * m + j)]) : (short)0;
    }
    const int uc = 8 * V + 4 * t + m;            // owned cell unit (tile t)
    #pragma unroll
    for (int rr = 0; rr < 4; ++rr) {
      const float sc = (rr == 2) ? (2.0f * L2E) : (-L2E);
      cb[t][rr] = sc * (Bi[rr * 32 + uc] + Bh[rr * 32 + uc]);
      w0x[t][rr] = isL1 ? 0.f : sc * Wih0[rr * 32 + uc];
    }
  }
  const float wfcA = isL1 ? Wfc[8 * V + m]     : 0.f;
  const float wfcB = isL1 ? Wfc[8 * V + 4 + m] : 0.f;

  float cvA = 0.f, cvB = 0.f, hA = 0.f, hB = 0.f;
  const float* xb = x + (size_t)(blockIdx.x * 16 + col) * SEQ;
  const int  rd = col * LSTR + 4 * m;                 // b128 read: units 8m..8m+7
  const int  wb = col * LSTR + 4 * V + (m >> 1);      // write: pair dword
  const bool wr = ((m & 1) == 0);                     // even-m lanes write

  for (int k = 0; k < SEQ / 4; ++k) {
    float4 xv = {0.f, 0.f, 0.f, 0.f};
    if (!isL1) xv = *reinterpret_cast<const float4*>(xb + k * 4);
    #pragma unroll
    for (int uu = 0; uu < 4; ++uu) {
      const int par = uu & 1;
      if (!isL1) {
        // ---- L0: h0(i) from h0(i-1) at parity (i+1)&1 ----
        const i32x4 hv = *(const i32x4*)&bufH0[par ^ 1][rd];
        const bf16x8 hf = __builtin_bit_cast(bf16x8, hv);
        f32x4 A0, A1;
        A0 = __builtin_amdgcn_mfma_f32_16x16x32_bf16(wfR[0], hf, cb[0], 0, 0, 0);
        A1 = __builtin_amdgcn_mfma_f32_16x16x32_bf16(wfR[1], hf, cb[1], 0, 0, 0);
        const float xt = (uu == 0) ? xv.x : (uu == 1) ? xv.y : (uu == 2) ? xv.z : xv.w;
        // regs ARE (i,f,g,o) of the owned units -- zero select
        CELL(fmaf(w0x[0][0], xt, A0[0]), fmaf(w0x[0][1], xt, A0[1]),
             fmaf(w0x[0][2], xt, A0[2]), fmaf(w0x[0][3], xt, A0[3]), cvA, hA);
        CELL(fmaf(w0x[1][0], xt, A1[0]), fmaf(w0x[1][1], xt, A1[1]),
             fmaf(w0x[1][2], xt, A1[2]), fmaf(w0x[1][3], xt, A1[3]), cvB, hB);
        int pkA, pkB;
        HPACK(hA, pkA);
        HPACK(hB, pkB);
        if (wr) { bufH0[par][wb] = pkA; bufH0[par][wb + 2] = pkB; }
      } else if (uu > 0 || k > 0) {
        // ---- L1: h1(i-1); reads h0(i-1) par^1, h1(i-2) par ----
        const i32x4 h0v = *(const i32x4*)&bufH0[par ^ 1][rd];
        const i32x4 h1v = *(const i32x4*)&bufH1[par][rd];
        const bf16x8 h0f = __builtin_bit_cast(bf16x8, h0v);
        const bf16x8 h1f = __builtin_bit_cast(bf16x8, h1v);
        f32x4 A0, A1;
        __builtin_amdgcn_s_setprio(1);
        A0 = __builtin_amdgcn_mfma_f32_16x16x32_bf16(wfI[0], h0f, cb[0], 0, 0, 0);
        A1 = __builtin_amdgcn_mfma_f32_16x16x32_bf16(wfI[1], h0f, cb[1], 0, 0, 0);
        A0 = __builtin_amdgcn_mfma_f32_16x16x32_bf16(wfR[0], h1f, A0, 0, 0, 0);
        A1 = __builtin_amdgcn_mfma_f32_16x16x32_bf16(wfR[1], h1f, A1, 0, 0, 0);
        __builtin_amdgcn_s_setprio(0);
        CELL(A0[0], A0[1], A0[2], A0[3], cvA, hA);
        CELL(A1[0], A1[1], A1[2], A1[3], cvB, hB);
        int pkA, pkB;
        HPACK(hA, pkA);
        HPACK(hB, pkB);
        if (wr) { bufH1[par ^ 1][wb] = pkA; bufH1[par ^ 1][wb + 2] = pkB; }
      }
      __syncthreads();
    }
  }

  // ---- epilogue: i = 512 for L1 -> h1(511); then FC + ReLU ----
  if (isL1) {
    const i32x4 h0v = *(const i32x4*)&bufH0[1][rd];   // h0(511), parity 1
    const i32x4 h1v = *(const i32x4*)&bufH1[0][rd];   // h1(510), parity 0
    const bf16x8 h0f = __builtin_bit_cast(bf16x8, h0v);
    const bf16x8 h1f = __builtin_bit_cast(bf16x8, h1v);
    f32x4 A0, A1;
    A0 = __builtin_amdgcn_mfma_f32_16x16x32_bf16(wfI[0], h0f, cb[0], 0, 0, 0);
    A1 = __builtin_amdgcn_mfma_f32_16x16x32_bf16(wfI[1], h0f, cb[1], 0, 0, 0);
    A0 = __builtin_amdgcn_mfma_f32_16x16x32_bf16(wfR[0], h1f, A0, 0, 0, 0);
    A1 = __builtin_amdgcn_mfma_f32_16x16x32_bf16(wfR[1], h1f, A1, 0, 0, 0);
    CELL(A0[0], A0[1], A0[2], A0[3], cvA, hA);
    CELL(A1[0], A1[1], A1[2], A1[3], cvB, hB);
    float part = hA * wfcA + hB * wfcB;
    part += __shfl_xor(part, 16);   // sum over m (lanes 16 apart)
    part += __shfl_xor(part, 32);
    if (l < 16) bufFC[V][l] = part;  // l<16 -> m==0, col=l
  }
  __syncthreads();
  if (w == 4 && l < 16) {
    const float o = bufFC[0][l] + bufFC[1][l] + bufFC[2][l] + bufFC[3][l] + bfc[0];
    out[blockIdx.x * 16 + l] = o > 0.f ? o : 0.f;
  }
}

extern "C" void kernel_launch(void* const* d_in, const int* in_sizes, int n_in,
                              void* d_out, int out_size, void* d_ws, size_t ws_size,
                              hipStream_t stream) {
  const float* x    = (const float*)d_in[0];
  const float* Wih0 = (const float*)d_in[1];
  const float* Whh0 = (const float*)d_in[2];
  const float* bih0 = (const float*)d_in[3];
  const float* bhh0 = (const float*)d_in[4];
  const float* Wih1 = (const float*)d_in[5];
  const float* Whh1 = (const float*)d_in[6];
  const float* bih1 = (const float*)d_in[7];
  const float* bhh1 = (const float*)d_in[8];
  const float* Wfc  = (const float*)d_in[9];
  const float* bfc  = (const float*)d_in[10];

  const int B = 4096;
  const int grid = B / 16;   // 256 blocks x 8 waves = 2048 waves -> 2/SIMD
  lstm2_zs_kernel<<<grid, 512, 0, stream>>>(
      x, Wih0, Whh0, bih0, bhh0, Wih1, Whh1, bih1, bhh1, Wfc, bfc,
      (float*)d_out);
}